// Round 8
// baseline (459.371 us; speedup 1.0000x reference)
//
#include <hip/hip_runtime.h>
#include <hip/hip_bf16.h>
#include <cstdint>
#include <cstddef>

// Problem: B=4, T=4096, D=1024, H=16, HD=64.
// qkv = x @ Wqkv; per-token 16x16 head attention; out = ao @ Wout.
//
// qkv/ao stored permuted per token (absorbed into weight transposes) so attn
// is fully coalesced. GEMMs: producer-consumer wave-specialized K-loop —
// 4 compute waves (no VMEM, no barriers) + 1 producer wave (global_load_lds,
// per-wave vmcnt only), double-buffered 2x32KB LDS, LDS flag handshake.
// XCD-band swizzle keeps the A-band L2-resident per XCD.

typedef __bf16 bf16x8 __attribute__((ext_vector_type(8)));
typedef __bf16 bf16x4 __attribute__((ext_vector_type(4)));
typedef float  f32x4  __attribute__((ext_vector_type(4)));

#define AS1 __attribute__((address_space(1)))
#define AS3 __attribute__((address_space(3)))

__device__ __forceinline__ void async_copy16(const void* g, void* l) {
    __builtin_amdgcn_global_load_lds((const AS1 void*)g, (AS3 void*)l, 16, 0, 0);
}

// permuted qkv layout (see R4): q/k A-frags at lane*8, V pre-transposed [d][j]
__device__ __forceinline__ int invp_qkv(int col) {
    int g = col >> 10;
    if (g == 2) { int q = col & 1023; return 2048 + ((q & 63) << 4) + (q >> 6); }
    int h = (col >> 6) & 15, d = col & 63;
    return (g << 10) + ((d & 32) << 4) + (((d >> 3) & 3) << 7) + (h << 3) + (d & 7);
}
// ao position map: attn lane stores its 16 C-layout values at lane*16
__device__ __forceinline__ int invp_ao(int k) {
    return (((k >> 8) & 3) << 8) + ((k & 15) << 4) + (((k >> 4) & 3) << 2) + ((k >> 6) & 3);
}

// ---------------- convert fp32 -> bf16 ----------------
__global__ __launch_bounds__(256) void cvt_bf16_kernel(const float4* __restrict__ in,
                                                       bf16x4* __restrict__ out, int n4) {
    int i = blockIdx.x * 256 + threadIdx.x;
    if (i >= n4) return;
    float4 v = in[i];
    bf16x4 o = { (__bf16)v.x, (__bf16)v.y, (__bf16)v.z, (__bf16)v.w };
    out[i] = o;
}

// ---------------- transpose + convert Wqkv (row order permuted) ----------------
__global__ __launch_bounds__(256) void transpose_qkv_kernel(const float* __restrict__ in,
                                                            __bf16* __restrict__ out) {
    __shared__ float tile[32][33];
    const int C = 3072;
    int c0 = blockIdx.x * 32, r0 = blockIdx.y * 32;
    int tx = threadIdx.x, ty = threadIdx.y;
    #pragma unroll
    for (int i = 0; i < 32; i += 8)
        tile[ty + i][tx] = in[(size_t)(r0 + ty + i) * C + c0 + tx];
    __syncthreads();
    #pragma unroll
    for (int i = 0; i < 32; i += 8) {
        int prow = invp_qkv(c0 + ty + i);
        out[(size_t)prow * 1024 + r0 + tx] = (__bf16)tile[tx][ty + i];
    }
}

// ---------------- transpose + convert Wout (k order permuted) ----------------
__global__ __launch_bounds__(256) void transpose_wout_kernel(const float* __restrict__ in,
                                                             __bf16* __restrict__ out) {
    __shared__ float tile[32][33];
    const int C = 1024;
    int c0 = blockIdx.x * 32, r0 = blockIdx.y * 32;
    int tx = threadIdx.x, ty = threadIdx.y;
    #pragma unroll
    for (int i = 0; i < 32; i += 8)
        tile[ty + i][tx] = in[(size_t)(r0 + ty + i) * C + c0 + tx];
    __syncthreads();
    int pk = invp_ao(r0 + tx);
    #pragma unroll
    for (int i = 0; i < 32; i += 8)
        out[(size_t)(c0 + ty + i) * 1024 + pk] = (__bf16)tile[tx][ty + i];
}

// ---------------- producer-consumer bf16 GEMM, C = A @ Bt^T ----------------
// 320 threads: waves 0-3 compute (2x2, 64x64 each, 4x4 mfma_16x16x32),
// wave 4 producer. BK=64, dbuf 2x(16+16) KB, LDS 128B rows, 8 16B slots,
// swizzle phys = slot ^ (row&7). Flags: ready[b] stamp, done[b] counter.
template<int OUT_BF16>
__global__ __launch_bounds__(320) void gemm_pc(const __bf16* __restrict__ A,
                                               const __bf16* __restrict__ Bt,
                                               void* __restrict__ Cv,
                                               int N, int K) {
    __shared__ __bf16 As[2][128 * 64]; // 2 x 16 KB
    __shared__ __bf16 Bs[2][128 * 64]; // 2 x 16 KB
    __shared__ int flags[8];           // [0..1]=ready stamp, [4..5]=done count

    const int lin = blockIdx.x;
    const int xcd = lin & 7;
    const int rr  = lin >> 3;
    const int by  = xcd * 16 + (rr & 15);
    const int bx  = rr >> 4;

    const int tid  = threadIdx.x;
    const int wave = tid >> 6;
    const int lane = tid & 63;

    if (tid == 0) { flags[0] = flags[1] = flags[4] = flags[5] = 0; }
    __syncthreads(); // only barrier in the kernel

    const int T = K >> 6; // BK=64 iterations

    if (wave == 4) {
        // ---- producer ----
        const int l8 = lane >> 3, l7 = lane & 7;
        const int koff = (l7 ^ l8) << 3; // swizzled k-element offset of this lane's 16B
        const __bf16* Ag = A  + (size_t)(by * 128 + l8) * K + koff;
        const __bf16* Bg = Bt + (size_t)(bx * 128 + l8) * K + koff;

        auto issue = [&](int t) {
            const int b = t & 1;
            const size_t kk = (size_t)t * 64;
            char* da = (char*)As[b];
            char* db = (char*)Bs[b];
            #pragma unroll
            for (int i = 0; i < 16; ++i)
                async_copy16(Ag + (size_t)i * 8 * K + kk, da + i * 1024);
            #pragma unroll
            for (int i = 0; i < 16; ++i)
                async_copy16(Bg + (size_t)i * 8 * K + kk, db + i * 1024);
        };

        issue(0);
        for (int t = 0; t < T; ++t) {
            if (t + 1 < T) {
                const int b1 = (t + 1) & 1;
                const int need = 4 * ((t + 1) >> 1); // iters of parity b1 before t+1, x4 waves
                while (__hip_atomic_load(&flags[4 + b1], __ATOMIC_ACQUIRE,
                                         __HIP_MEMORY_SCOPE_WORKGROUP) < need) {}
                issue(t + 1);
                __builtin_amdgcn_s_waitcnt(0x8F70); // vmcnt(32): tile t fully landed
            } else {
                __builtin_amdgcn_s_waitcnt(0x0F70); // vmcnt(0)
            }
            if (lane == 0)
                __hip_atomic_store(&flags[t & 1], t + 1, __ATOMIC_RELEASE,
                                   __HIP_MEMORY_SCOPE_WORKGROUP);
        }
    } else {
        // ---- compute waves 0..3 ----
        const int quad = lane >> 4;
        const int q16  = lane & 15;
        const int wr   = wave >> 1, wc = wave & 1;
        const int rx   = q16 & 7; // row&7 for frag rows

        f32x4 acc[4][4] = {};

        for (int t = 0; t < T; ++t) {
            const int b = t & 1;
            while (__hip_atomic_load(&flags[b], __ATOMIC_ACQUIRE,
                                     __HIP_MEMORY_SCOPE_WORKGROUP) < t + 1) {}
            const char* Ab = (const char*)As[b];
            const char* Bb = (const char*)Bs[b];
            #pragma unroll
            for (int s = 0; s < 2; ++s) {
                const int ps = s * 4 + quad; // logical k-slot
                bf16x8 af[4], bfr[4];
                #pragma unroll
                for (int mi = 0; mi < 4; ++mi) {
                    int row = wr * 64 + mi * 16 + q16;
                    af[mi] = *(const bf16x8*)(Ab + row * 128 + ((ps ^ rx) << 4));
                }
                #pragma unroll
                for (int ni = 0; ni < 4; ++ni) {
                    int row = wc * 64 + ni * 16 + q16;
                    bfr[ni] = *(const bf16x8*)(Bb + row * 128 + ((ps ^ rx) << 4));
                }
                #pragma unroll
                for (int mi = 0; mi < 4; ++mi)
                    #pragma unroll
                    for (int ni = 0; ni < 4; ++ni)
                        acc[mi][ni] = __builtin_amdgcn_mfma_f32_16x16x32_bf16(af[mi], bfr[ni], acc[mi][ni], 0, 0, 0);
            }
            if (lane == 0)
                __hip_atomic_fetch_add(&flags[4 + b], 1, __ATOMIC_ACQ_REL,
                                       __HIP_MEMORY_SCOPE_WORKGROUP);
        }

        // epilogue: D row = quad*4 + r, col = q16 (per 16x16 tile)
        const int row0 = by * 128, col0 = bx * 128;
        #pragma unroll
        for (int mi = 0; mi < 4; ++mi) {
            #pragma unroll
            for (int ni = 0; ni < 4; ++ni) {
                int col = col0 + wc * 64 + ni * 16 + q16;
                #pragma unroll
                for (int r = 0; r < 4; ++r) {
                    int row = row0 + wr * 64 + mi * 16 + quad * 4 + r;
                    if (OUT_BF16)
                        ((__bf16*)Cv)[(size_t)row * N + col] = (__bf16)acc[mi][ni][r];
                    else
                        ((float*)Cv)[(size_t)row * N + col] = acc[mi][ni][r];
                }
            }
        }
    }
}

// ---------------- per-token head attention, MFMA, one wave per token ----------------
__global__ __launch_bounds__(256) void attn_mfma_kernel(const __bf16* __restrict__ qkv,
                                                        __bf16* __restrict__ ao) {
    const int tok  = blockIdx.x * 4 + (threadIdx.x >> 6);
    const int lane = threadIdx.x & 63;
    const int quad = lane >> 4;
    const int q16  = lane & 15;

    const __bf16* base = qkv + (size_t)tok * 3072;

    const bf16x8 qf0 = *(const bf16x8*)(base + lane * 8);
    const bf16x8 qf1 = *(const bf16x8*)(base + 512 + lane * 8);
    const bf16x8 kf0 = *(const bf16x8*)(base + 1024 + lane * 8);
    const bf16x8 kf1 = *(const bf16x8*)(base + 1536 + lane * 8);

    f32x4 st = {0.f, 0.f, 0.f, 0.f};
    st = __builtin_amdgcn_mfma_f32_16x16x32_bf16(kf0, qf0, st, 0, 0, 0);
    st = __builtin_amdgcn_mfma_f32_16x16x32_bf16(kf1, qf1, st, 0, 0, 0);

    float s0 = st[0] * 0.125f, s1 = st[1] * 0.125f, s2 = st[2] * 0.125f, s3 = st[3] * 0.125f;
    float m = fmaxf(fmaxf(s0, s1), fmaxf(s2, s3));
    m = fmaxf(m, __shfl_xor(m, 16));
    m = fmaxf(m, __shfl_xor(m, 32));
    float e0 = __expf(s0 - m), e1 = __expf(s1 - m), e2 = __expf(s2 - m), e3 = __expf(s3 - m);
    float sum = e0 + e1 + e2 + e3;
    sum += __shfl_xor(sum, 16);
    sum += __shfl_xor(sum, 32);
    const float inv = 1.f / sum;

    union { __bf16 h[2]; int i; } u01, u23;
    u01.h[0] = (__bf16)(e0 * inv); u01.h[1] = (__bf16)(e1 * inv);
    u23.h[0] = (__bf16)(e2 * inv); u23.h[1] = (__bf16)(e3 * inv);

    const int src0 = quad * 32 + q16;
    const int src1 = src0 + 16;
    union { int i[4]; bf16x8 v; } af;
    af.i[0] = __shfl(u01.i, src0);
    af.i[1] = __shfl(u23.i, src0);
    af.i[2] = __shfl(u01.i, src1);
    af.i[3] = __shfl(u23.i, src1);
    if (quad >= 2) { af.i[0] = 0; af.i[1] = 0; af.i[2] = 0; af.i[3] = 0; }

    const __bf16* vb = base + 2048;
    f32x4 accs[4];
    #pragma unroll
    for (int c = 0; c < 4; ++c) {
        bf16x8 bfv = {};
        if (quad < 2)
            bfv = *(const bf16x8*)(vb + (c * 16 + q16) * 16 + quad * 8);
        f32x4 z = {0.f, 0.f, 0.f, 0.f};
        accs[c] = __builtin_amdgcn_mfma_f32_16x16x32_bf16(af.v, bfv, z, 0, 0, 0);
    }

    union { __bf16 h[16]; bf16x8 v[2]; } o;
    #pragma unroll
    for (int c = 0; c < 4; ++c)
        #pragma unroll
        for (int r = 0; r < 4; ++r)
            o.h[c * 4 + r] = (__bf16)accs[c][r];
    __bf16* outp = ao + (size_t)tok * 1024 + lane * 16;
    *(bf16x8*)outp = o.v[0];
    *(bf16x8*)(outp + 8) = o.v[1];
}

// ---------------- launch ----------------
extern "C" void kernel_launch(void* const* d_in, const int* in_sizes, int n_in,
                              void* d_out, int out_size, void* d_ws, size_t ws_size,
                              hipStream_t stream) {
    const float* x    = (const float*)d_in[0]; // 16384 x 1024
    const float* Wqkv = (const float*)d_in[1]; // 1024 x 3072
    const float* Wout = (const float*)d_in[2]; // 1024 x 1024
    float* out = (float*)d_out;                // 16384 x 1024

    char* ws = (char*)d_ws;
    __bf16* xb    = (__bf16*)(ws);                                   // 32 MiB
    __bf16* wqkvT = (__bf16*)(ws + 33554432);                        // 6 MiB
    __bf16* woutT = (__bf16*)(ws + 33554432 + 6291456);              // 2 MiB
    __bf16* qkv   = (__bf16*)(ws + 33554432 + 6291456 + 2097152);    // 96 MiB
    __bf16* ao    = (__bf16*)(ws + 33554432 + 6291456 + 2097152 + 100663296); // 32 MiB

    cvt_bf16_kernel<<<16384, 256, 0, stream>>>((const float4*)x, (bf16x4*)xb, 4194304);
    transpose_qkv_kernel<<<dim3(96, 32), dim3(32, 8), 0, stream>>>(Wqkv, wqkvT);
    transpose_wout_kernel<<<dim3(32, 32), dim3(32, 8), 0, stream>>>(Wout, woutT);
    // GEMM1: qkv = xb @ wqkvT^T (16384 x 3072), producer-consumer, XCD-band swizzle
    gemm_pc<1><<<24 * 128, 320, 0, stream>>>(xb, wqkvT, (void*)qkv, 3072, 1024);
    attn_mfma_kernel<<<4096, 256, 0, stream>>>(qkv, ao);
    // GEMM2: out = ao @ woutT^T (fp32 out)
    gemm_pc<0><<<8 * 128, 320, 0, stream>>>(ao, woutT, (void*)out, 1024, 1024);
}